// Round 1
// baseline (431.179 us; speedup 1.0000x reference)
//
#include <hip/hip_runtime.h>
#include <hip/hip_bf16.h>
#include <math.h>

typedef __attribute__((ext_vector_type(4))) float f32x4;
typedef __attribute__((ext_vector_type(8))) short bf16x8;
typedef unsigned short u16;

__device__ __forceinline__ u16 bfbits(float f) {
  union { __hip_bfloat16 h; u16 u; } cv;
  cv.h = __float2bfloat16(f);
  return cv.u;
}

__device__ __forceinline__ float acos_fast(float x) {
  float a = fabsf(x);
  float p = fmaf(a, -0.0187293f, 0.0742610f);
  p = fmaf(a, p, -0.2121144f);
  p = fmaf(a, p, 1.5707288f);
  float r = sqrtf(fmaxf(1.f - a, 0.f)) * p;
  return x < 0.f ? 3.14159265358979f - r : r;
}

// ---------------- weight fp32 -> bf16 (single fused kernel) ----------------
__global__ __launch_bounds__(256) void convert_weights(
    const float* __restrict__ wq, const float* __restrict__ wk, const float* __restrict__ wv,
    const float* __restrict__ wo, const float* __restrict__ w1, const float* __restrict__ w2,
    u16* __restrict__ owq, u16* __restrict__ owk, u16* __restrict__ owv,
    u16* __restrict__ owo, u16* __restrict__ ow1, u16* __restrict__ ow2) {
  int i = blockIdx.x * 256 + threadIdx.x;  // float4 index, total 614400
  const float* src; u16* dst; int base;
  if (i < 8192)        { src = wq; dst = owq; base = 0; }
  else if (i < 16384)  { src = wk; dst = owk; base = 8192; }
  else if (i < 24576)  { src = wv; dst = owv; base = 16384; }
  else if (i < 90112)  { src = wo; dst = owo; base = 24576; }
  else if (i < 352256) { src = w1; dst = ow1; base = 90112; }
  else                 { src = w2; dst = ow2; base = 352256; }
  int li = i - base;
  float4 v = reinterpret_cast<const float4*>(src)[li];
  ushort4 o;
  o.x = bfbits(v.x); o.y = bfbits(v.y); o.z = bfbits(v.z); o.w = bfbits(v.w);
  reinterpret_cast<ushort4*>(dst)[li] = o;
}

// ---------------- layernorm (one row per block, 128 threads) ----------------
__global__ __launch_bounds__(128) void ln_kernel(const float* __restrict__ x,
    const float* __restrict__ w, const float* __restrict__ b, u16* __restrict__ out) {
  int row = blockIdx.x, tid = threadIdx.x;
  float4 v = reinterpret_cast<const float4*>(x + row * 512)[tid];
  float s  = v.x + v.y + v.z + v.w;
  float s2 = v.x*v.x + v.y*v.y + v.z*v.z + v.w*v.w;
  #pragma unroll
  for (int o = 32; o > 0; o >>= 1) { s += __shfl_down(s, o); s2 += __shfl_down(s2, o); }
  __shared__ float sm[4];
  if ((tid & 63) == 0) { sm[(tid >> 6)*2] = s; sm[(tid >> 6)*2 + 1] = s2; }
  __syncthreads();
  float ts = sm[0] + sm[2], ts2 = sm[1] + sm[3];
  float mean = ts * (1.f/512.f);
  float var  = ts2 * (1.f/512.f) - mean*mean;
  float rstd = rsqrtf(var + 1e-5f);
  float4 wv = reinterpret_cast<const float4*>(w)[tid];
  float4 bv = reinterpret_cast<const float4*>(b)[tid];
  ushort4 o;
  o.x = bfbits((v.x-mean)*rstd*wv.x + bv.x);
  o.y = bfbits((v.y-mean)*rstd*wv.y + bv.y);
  o.z = bfbits((v.z-mean)*rstd*wv.z + bv.z);
  o.w = bfbits((v.w-mean)*rstd*wv.w + bv.w);
  reinterpret_cast<ushort4*>(out + row * 512)[tid] = o;
}

// ---------------- QKV projection (per-head 64x64 GEMM, MFMA) ----------------
// q,k stored [bh][s][e] bf16; v stored transposed [bh][e][s] bf16.
// Also emits qsq/ksq = row norms^2 from the bf16-rounded values.
__global__ __launch_bounds__(256) void qkv_kernel(const u16* __restrict__ h1,
    const u16* __restrict__ wqb, const u16* __restrict__ wkb, const u16* __restrict__ wvb,
    u16* __restrict__ q, u16* __restrict__ k, u16* __restrict__ vt,
    float* __restrict__ qsq, float* __restrict__ ksq) {
  int mt = blockIdx.x, head = blockIdx.y, mat = blockIdx.z;
  int wave = threadIdx.x >> 6, lane = threadIdx.x & 63;
  int lr = lane & 15, lg = lane >> 4;
  int m0 = mt * 64 + wave * 16;
  const u16* W = (mat == 0 ? wqb : mat == 1 ? wkb : wvb) + head * 4096;
  const u16* xr = h1 + (m0 + lr) * 512 + head * 64 + lg * 8;
  bf16x8 a0 = *reinterpret_cast<const bf16x8*>(xr);
  bf16x8 a1 = *reinterpret_cast<const bf16x8*>(xr + 32);
  f32x4 acc[4];
  #pragma unroll
  for (int c = 0; c < 4; c++)
    #pragma unroll
    for (int j = 0; j < 4; j++) acc[c][j] = 0.f;
  #pragma unroll
  for (int c = 0; c < 4; c++) {
    const u16* wr = W + (c*16 + lr) * 64 + lg * 8;
    bf16x8 b0 = *reinterpret_cast<const bf16x8*>(wr);
    bf16x8 b1 = *reinterpret_cast<const bf16x8*>(wr + 32);
    acc[c] = __builtin_amdgcn_mfma_f32_16x16x32_bf16(a0, b0, acc[c], 0, 0, 0);
    acc[c] = __builtin_amdgcn_mfma_f32_16x16x32_bf16(a1, b1, acc[c], 0, 0, 0);
  }
  int m_base = m0 + 4*lg;
  int bq = m_base >> 10;
  int s_base = m_base & 1023;
  int bh = (bq << 3) + head;
  if (mat == 2) {
    #pragma unroll
    for (int c = 0; c < 4; c++)
      #pragma unroll
      for (int j = 0; j < 4; j++)
        vt[(bh*64 + c*16 + lr) * 1024 + s_base + j] = bfbits(acc[c][j]);
  } else {
    u16* dst = (mat == 0 ? q : k);
    float* sq = (mat == 0 ? qsq : ksq);
    float ss[4] = {0.f, 0.f, 0.f, 0.f};
    #pragma unroll
    for (int c = 0; c < 4; c++)
      #pragma unroll
      for (int j = 0; j < 4; j++) {
        float vv = acc[c][j];
        dst[(bh*1024 + s_base + j) * 64 + c*16 + lr] = bfbits(vv);
        ss[j] += vv * vv;
      }
    #pragma unroll
    for (int j = 0; j < 4; j++) {
      #pragma unroll
      for (int o = 1; o < 16; o <<= 1) ss[j] += __shfl_xor(ss[j], o);
    }
    if (lr == 0) {
      #pragma unroll
      for (int j = 0; j < 4; j++) sq[bh*1024 + s_base + j] = ss[j];
    }
  }
}

// ---------------- fused product-manifold attention (flash-style) ----------------
__global__ __launch_bounds__(256) void attn_kernel(
    const u16* __restrict__ q, const u16* __restrict__ k, const u16* __restrict__ vt,
    const float* __restrict__ qsqA, const float* __restrict__ ksqA,
    const float* __restrict__ gw, const float* __restrict__ temp,
    u16* __restrict__ attnb) {
  int bh = blockIdx.y;
  int b = bh >> 3, head = bh & 7;
  int wave = threadIdx.x >> 6, lane = threadIdx.x & 63;
  int lr = lane & 15, lg = lane >> 4;
  int q0 = blockIdx.x * 64 + wave * 16;
  const u16* qp = q  + bh * 65536;
  const u16* kp = k  + bh * 65536;
  const u16* vp = vt + bh * 65536;
  const float* qsq = qsqA + bh * 1024;
  const float* ksq = ksqA + bh * 1024;
  // per-head geometry mixing: softmax(gw) * temp  (INV_SQRT == 1.0f in fp32)
  float g0 = gw[head*3], g1 = gw[head*3+1], g2 = gw[head*3+2];
  float gm = fmaxf(g0, fmaxf(g1, g2));
  float e0 = __expf(g0-gm), e1 = __expf(g1-gm), e2 = __expf(g2-gm);
  float gi = 1.f / (e0 + e1 + e2);
  float tmp = temp[head];
  float ch = e0*gi*tmp, ce = e1*gi*tmp, cs = e2*gi*tmp;

  const u16* qr = qp + (q0 + lr) * 64 + lg * 8;
  bf16x8 aq0 = *reinterpret_cast<const bf16x8*>(qr);
  bf16x8 aq1 = *reinterpret_cast<const bf16x8*>(qr + 32);

  float qs[4], omq[4], rqn[4];
  #pragma unroll
  for (int j = 0; j < 4; j++) {
    float v = qsq[q0 + 4*lg + j];
    qs[j] = v; omq[j] = 1.f - v; rqn[j] = 1.f / (sqrtf(v) + 1e-8f);
  }
  float mrun[4], lrun[4];
  f32x4 acc[4];
  #pragma unroll
  for (int j = 0; j < 4; j++) { mrun[j] = -1e30f; lrun[j] = 0.f; }
  #pragma unroll
  for (int c = 0; c < 4; c++)
    #pragma unroll
    for (int j = 0; j < 4; j++) acc[c][j] = 0.f;

  // per-wave P transpose buffer: 16 rows x 40 shorts (stride 80B keeps b128 16B-aligned)
  __shared__ u16 plds[4][16*40];
  u16* pw = &plds[wave][0];

  for (int t0 = 0; t0 < 1024; t0 += 32) {
    f32x4 sc[2];
    float kq[2], omk[2], rkn[2];
    #pragma unroll
    for (int tc = 0; tc < 2; tc++) {
      const u16* kr = kp + (t0 + tc*16 + lr) * 64 + lg * 8;
      bf16x8 b0 = *reinterpret_cast<const bf16x8*>(kr);
      bf16x8 b1 = *reinterpret_cast<const bf16x8*>(kr + 32);
      f32x4 z;
      #pragma unroll
      for (int j = 0; j < 4; j++) z[j] = 0.f;
      z = __builtin_amdgcn_mfma_f32_16x16x32_bf16(aq0, b0, z, 0, 0, 0);
      z = __builtin_amdgcn_mfma_f32_16x16x32_bf16(aq1, b1, z, 0, 0, 0);
      sc[tc] = z;
      float kv = ksq[t0 + tc*16 + lr];
      kq[tc] = kv; omk[tc] = 1.f - kv; rkn[tc] = 1.f / (sqrtf(kv) + 1e-8f);
    }
    float tmax[4];
    #pragma unroll
    for (int j = 0; j < 4; j++) tmax[j] = -1e30f;
    #pragma unroll
    for (int tc = 0; tc < 2; tc++) {
      #pragma unroll
      for (int j = 0; j < 4; j++) {
        float qkd = sc[tc][j];
        float dsq = fmaxf(qs[j] + kq[tc] - 2.f*qkd, 0.f);
        float euc = sqrtf(dsq + 1e-8f);
        float denom = omq[j]*omk[tc] + 1e-8f;
        float u = 2.f * dsq / denom;
        u = fminf(fmaxf(u, 0.f), 999999.f);           // == clip(cosh_arg,1,1e6)-1
        float hyp = __logf(1.f + u + sqrtf(u*(u + 2.f)));  // acosh(1+u)
        float ca = qkd * rqn[j] * rkn[tc];
        ca = fminf(fmaxf(ca, -1.f), 1.f);             // fp32(-1+1e-8) == -1
        float sph = acos_fast(ca);
        float sim = -(ch*hyp + ce*euc + cs*sph);
        sc[tc][j] = sim;
        tmax[j] = fmaxf(tmax[j], sim);
      }
    }
    #pragma unroll
    for (int j = 0; j < 4; j++) {
      #pragma unroll
      for (int o = 1; o < 16; o <<= 1) tmax[j] = fmaxf(tmax[j], __shfl_xor(tmax[j], o));
    }
    float sca[4], ps[4];
    #pragma unroll
    for (int j = 0; j < 4; j++) {
      float mnew = fmaxf(mrun[j], tmax[j]);
      sca[j] = __expf(mrun[j] - mnew);
      mrun[j] = mnew;
      ps[j] = 0.f;
    }
    #pragma unroll
    for (int tc = 0; tc < 2; tc++)
      #pragma unroll
      for (int j = 0; j < 4; j++) {
        float p = __expf(sc[tc][j] - mrun[j]);
        sc[tc][j] = p;
        ps[j] += p;
      }
    #pragma unroll
    for (int j = 0; j < 4; j++) {
      #pragma unroll
      for (int o = 1; o < 16; o <<= 1) ps[j] += __shfl_xor(ps[j], o);
      lrun[j] = lrun[j]*sca[j] + ps[j];
    }
    #pragma unroll
    for (int c = 0; c < 4; c++)
      #pragma unroll
      for (int j = 0; j < 4; j++) acc[c][j] *= sca[j];
    // P (D-layout) -> LDS -> A-fragment layout
    #pragma unroll
    for (int tc = 0; tc < 2; tc++)
      #pragma unroll
      for (int j = 0; j < 4; j++)
        pw[(4*lg + j)*40 + tc*16 + lr] = bfbits(sc[tc][j]);
    bf16x8 pa = *reinterpret_cast<const bf16x8*>(pw + lr*40 + lg*8);
    #pragma unroll
    for (int c = 0; c < 4; c++) {
      bf16x8 bv = *reinterpret_cast<const bf16x8*>(vp + (c*16 + lr)*1024 + t0 + lg*8);
      acc[c] = __builtin_amdgcn_mfma_f32_16x16x32_bf16(pa, bv, acc[c], 0, 0, 0);
    }
  }
  float rl[4];
  #pragma unroll
  for (int j = 0; j < 4; j++) rl[j] = 1.f / lrun[j];
  #pragma unroll
  for (int c = 0; c < 4; c++)
    #pragma unroll
    for (int j = 0; j < 4; j++)
      attnb[((b << 10) + q0 + 4*lg + j)*512 + head*64 + c*16 + lr] = bfbits(acc[c][j]*rl[j]);
}

// ---------------- generic  Y = epilogue(X @ W^T + bias)  (bf16 MFMA) ----------------
// MODE 0: outf = acc + bias + res          (Wo projection + residual, fp32 out)
// MODE 1: outb = bf16(gelu(acc + bias))    (FF1)
// MODE 2: outf = acc + bias + res          (FF2 + residual -> d_out) + gw softmax
template<int K, int MODE>
__global__ __launch_bounds__(256) void gemm_kernel(
    const u16* __restrict__ X, const u16* __restrict__ W,
    const float* __restrict__ bias, const float* __restrict__ res,
    float* __restrict__ outf, u16* __restrict__ outb,
    const float* __restrict__ gw, float* __restrict__ wout) {
  constexpr int NS = (MODE == 1) ? 2048 : 512;
  int wave = threadIdx.x >> 6, lane = threadIdx.x & 63;
  int lr = lane & 15, lg = lane >> 4;
  int m0 = blockIdx.x * 64 + wave * 16;
  int n0 = blockIdx.y * 64;
  f32x4 acc[4];
  #pragma unroll
  for (int c = 0; c < 4; c++)
    #pragma unroll
    for (int j = 0; j < 4; j++) acc[c][j] = 0.f;
  const u16* Xr = X + (m0 + lr) * K + lg * 8;
  const u16* Wr = W + (n0 + lr) * K + lg * 8;
  #pragma unroll 4
  for (int kk = 0; kk < K; kk += 32) {
    bf16x8 a = *reinterpret_cast<const bf16x8*>(Xr + kk);
    #pragma unroll
    for (int c = 0; c < 4; c++) {
      bf16x8 bw = *reinterpret_cast<const bf16x8*>(Wr + c*16*K + kk);
      acc[c] = __builtin_amdgcn_mfma_f32_16x16x32_bf16(a, bw, acc[c], 0, 0, 0);
    }
  }
  #pragma unroll
  for (int c = 0; c < 4; c++) {
    int col = n0 + c*16 + lr;
    float bb = bias[col];
    #pragma unroll
    for (int j = 0; j < 4; j++) {
      int row = m0 + 4*lg + j;
      float v = acc[c][j] + bb;
      if (MODE == 0 || MODE == 2) {
        outf[row*NS + col] = v + res[row*NS + col];
      } else {
        float g = 0.5f * v * (1.f + erff(v * 0.70710678118f));
        outb[row*NS + col] = bfbits(g);
      }
    }
  }
  if (MODE == 2) {
    if (blockIdx.x == 0 && blockIdx.y == 0 && threadIdx.x < 8) {
      int h = threadIdx.x;
      float a0 = gw[h*3], a1 = gw[h*3+1], a2 = gw[h*3+2];
      float m = fmaxf(a0, fmaxf(a1, a2));
      float x0 = __expf(a0-m), x1 = __expf(a1-m), x2 = __expf(a2-m);
      float inv = 1.f / (x0 + x1 + x2);
      wout[h*3+0] = x0*inv; wout[h*3+1] = x1*inv; wout[h*3+2] = x2*inv;
    }
  }
}

extern "C" void kernel_launch(void* const* d_in, const int* in_sizes, int n_in,
                              void* d_out, int out_size, void* d_ws, size_t ws_size,
                              hipStream_t stream) {
  const float* x    = (const float*)d_in[0];
  const float* Wq   = (const float*)d_in[1];
  const float* Wk   = (const float*)d_in[2];
  const float* Wv   = (const float*)d_in[3];
  const float* gw   = (const float*)d_in[4];
  const float* temp = (const float*)d_in[5];
  const float* Wo   = (const float*)d_in[6];
  const float* bo   = (const float*)d_in[7];
  const float* ln1w = (const float*)d_in[8];
  const float* ln1b = (const float*)d_in[9];
  const float* ln2w = (const float*)d_in[10];
  const float* ln2b = (const float*)d_in[11];
  const float* W1   = (const float*)d_in[12];
  const float* b1   = (const float*)d_in[13];
  const float* W2   = (const float*)d_in[14];
  const float* b2   = (const float*)d_in[15];

  char* ws = (char*)d_ws;
  u16*  wqb  = (u16*)(ws + 0);
  u16*  wkb  = (u16*)(ws + 65536);
  u16*  wvb  = (u16*)(ws + 131072);
  u16*  wob  = (u16*)(ws + 196608);
  u16*  w1b  = (u16*)(ws + 720896);
  u16*  w2b  = (u16*)(ws + 2818048);
  u16*  h1b  = (u16*)(ws + 4915200);
  u16*  qb   = (u16*)(ws + 9109504);
  u16*  kb   = (u16*)(ws + 13303808);
  u16*  vtb  = (u16*)(ws + 17498112);
  float* qsq = (float*)(ws + 21692416);
  float* ksq = (float*)(ws + 21823488);
  u16*  attnb= (u16*)(ws + 21954560);
  float* x1  = (float*)(ws + 26148864);
  u16*  h2b  = (u16*)(ws + 34537472);
  u16*  gb   = (u16*)(ws + 4915200);   // aliases h1b/qb/kb/vtb (dead before FF1)

  float* outf = (float*)d_out;
  float* wout = outf + 4096*512;

  convert_weights<<<2400, 256, 0, stream>>>(Wq, Wk, Wv, Wo, W1, W2,
                                            wqb, wkb, wvb, wob, w1b, w2b);
  ln_kernel<<<4096, 128, 0, stream>>>(x, ln1w, ln1b, h1b);
  qkv_kernel<<<dim3(64, 8, 3), 256, 0, stream>>>(h1b, wqb, wkb, wvb, qb, kb, vtb, qsq, ksq);
  attn_kernel<<<dim3(16, 32), 256, 0, stream>>>(qb, kb, vtb, qsq, ksq, gw, temp, attnb);
  gemm_kernel<512, 0><<<dim3(64, 8), 256, 0, stream>>>(attnb, wob, bo, x, x1, nullptr, nullptr, nullptr);
  ln_kernel<<<4096, 128, 0, stream>>>(x1, ln2w, ln2b, h2b);
  gemm_kernel<512, 1><<<dim3(64, 32), 256, 0, stream>>>(h2b, w1b, b1, nullptr, nullptr, gb, nullptr, nullptr);
  gemm_kernel<2048, 2><<<dim3(64, 8), 256, 0, stream>>>(gb, w2b, b2, x1, outf, nullptr, gw, wout);
}

// Round 2
// 291.943 us; speedup vs baseline: 1.4769x; 1.4769x over previous
//
#include <hip/hip_runtime.h>
#include <hip/hip_bf16.h>
#include <math.h>

typedef __attribute__((ext_vector_type(4))) float f32x4;
typedef __attribute__((ext_vector_type(8))) short bf16x8;
typedef unsigned short u16;
typedef unsigned int u32;

typedef f32x4  __attribute__((may_alias)) f32x4a;
typedef bf16x8 __attribute__((may_alias)) bf16x8a;
typedef uint2  __attribute__((may_alias)) uint2a;

__device__ __forceinline__ u16 bfbits(float f) {
  union { __hip_bfloat16 h; u16 u; } cv;
  cv.h = __float2bfloat16(f);
  return cv.u;
}
__device__ __forceinline__ float rcp_r(float x)  { return __builtin_amdgcn_rcpf(x); }
__device__ __forceinline__ float sqrt_r(float x) { return __builtin_amdgcn_sqrtf(x); }
__device__ __forceinline__ float log2_r(float x) { return __builtin_amdgcn_logf(x); }
__device__ __forceinline__ float exp2_r(float x) { return __builtin_amdgcn_exp2f(x); }
__device__ __forceinline__ u32 cvt_pk_bf16(float lo, float hi) {
  u32 r;
  asm("v_cvt_pk_bf16_f32 %0, %1, %2" : "=v"(r) : "v"(lo), "v"(hi));
  return r;
}

// ---------------- weight fp32 -> bf16 ----------------
__global__ __launch_bounds__(256) void convert_weights(
    const float* __restrict__ wq, const float* __restrict__ wk, const float* __restrict__ wv,
    const float* __restrict__ wo, const float* __restrict__ w1, const float* __restrict__ w2,
    u16* __restrict__ owq, u16* __restrict__ owk, u16* __restrict__ owv,
    u16* __restrict__ owo, u16* __restrict__ ow1, u16* __restrict__ ow2) {
  int i = blockIdx.x * 256 + threadIdx.x;  // float4 index, total 614400
  const float* src; u16* dst; int base;
  if (i < 8192)        { src = wq; dst = owq; base = 0; }
  else if (i < 16384)  { src = wk; dst = owk; base = 8192; }
  else if (i < 24576)  { src = wv; dst = owv; base = 16384; }
  else if (i < 90112)  { src = wo; dst = owo; base = 24576; }
  else if (i < 352256) { src = w1; dst = ow1; base = 90112; }
  else                 { src = w2; dst = ow2; base = 352256; }
  int li = i - base;
  float4 v = reinterpret_cast<const float4*>(src)[li];
  ushort4 o;
  o.x = bfbits(v.x); o.y = bfbits(v.y); o.z = bfbits(v.z); o.w = bfbits(v.w);
  reinterpret_cast<ushort4*>(dst)[li] = o;
}

// ---------------- layernorm ----------------
__global__ __launch_bounds__(128) void ln_kernel(const float* __restrict__ x,
    const float* __restrict__ w, const float* __restrict__ b, u16* __restrict__ out) {
  int row = blockIdx.x, tid = threadIdx.x;
  float4 v = reinterpret_cast<const float4*>(x + row * 512)[tid];
  float s  = v.x + v.y + v.z + v.w;
  float s2 = v.x*v.x + v.y*v.y + v.z*v.z + v.w*v.w;
  #pragma unroll
  for (int o = 32; o > 0; o >>= 1) { s += __shfl_down(s, o); s2 += __shfl_down(s2, o); }
  __shared__ float sm[4];
  if ((tid & 63) == 0) { sm[(tid >> 6)*2] = s; sm[(tid >> 6)*2 + 1] = s2; }
  __syncthreads();
  float ts = sm[0] + sm[2], ts2 = sm[1] + sm[3];
  float mean = ts * (1.f/512.f);
  float var  = ts2 * (1.f/512.f) - mean*mean;
  float rstd = __builtin_amdgcn_rsqf(var + 1e-5f);
  float4 wv = reinterpret_cast<const float4*>(w)[tid];
  float4 bv = reinterpret_cast<const float4*>(b)[tid];
  ushort4 o;
  o.x = bfbits((v.x-mean)*rstd*wv.x + bv.x);
  o.y = bfbits((v.y-mean)*rstd*wv.y + bv.y);
  o.z = bfbits((v.z-mean)*rstd*wv.z + bv.z);
  o.w = bfbits((v.w-mean)*rstd*wv.w + bv.w);
  reinterpret_cast<ushort4*>(out + row * 512)[tid] = o;
}

// ---------------- QKV projection ----------------
__global__ __launch_bounds__(256) void qkv_kernel(const u16* __restrict__ h1,
    const u16* __restrict__ wqb, const u16* __restrict__ wkb, const u16* __restrict__ wvb,
    u16* __restrict__ q, u16* __restrict__ k, u16* __restrict__ vt,
    float* __restrict__ qsq, float* __restrict__ ksq) {
  int mt = blockIdx.x, head = blockIdx.y, mat = blockIdx.z;
  int wave = threadIdx.x >> 6, lane = threadIdx.x & 63;
  int lr = lane & 15, lg = lane >> 4;
  int m0 = mt * 64 + wave * 16;
  const u16* W = (mat == 0 ? wqb : mat == 1 ? wkb : wvb) + head * 4096;
  const u16* xr = h1 + (m0 + lr) * 512 + head * 64 + lg * 8;
  bf16x8 a0 = *reinterpret_cast<const bf16x8a*>(xr);
  bf16x8 a1 = *reinterpret_cast<const bf16x8a*>(xr + 32);
  f32x4 acc[4];
  #pragma unroll
  for (int c = 0; c < 4; c++)
    #pragma unroll
    for (int j = 0; j < 4; j++) acc[c][j] = 0.f;
  #pragma unroll
  for (int c = 0; c < 4; c++) {
    const u16* wr = W + (c*16 + lr) * 64 + lg * 8;
    bf16x8 b0 = *reinterpret_cast<const bf16x8a*>(wr);
    bf16x8 b1 = *reinterpret_cast<const bf16x8a*>(wr + 32);
    acc[c] = __builtin_amdgcn_mfma_f32_16x16x32_bf16(a0, b0, acc[c], 0, 0, 0);
    acc[c] = __builtin_amdgcn_mfma_f32_16x16x32_bf16(a1, b1, acc[c], 0, 0, 0);
  }
  int m_base = m0 + 4*lg;
  int bq = m_base >> 10;
  int s_base = m_base & 1023;
  int bh = (bq << 3) + head;
  if (mat == 2) {
    #pragma unroll
    for (int c = 0; c < 4; c++)
      #pragma unroll
      for (int j = 0; j < 4; j++)
        vt[(bh*64 + c*16 + lr) * 1024 + s_base + j] = bfbits(acc[c][j]);
  } else {
    u16* dst = (mat == 0 ? q : k);
    float* sq = (mat == 0 ? qsq : ksq);
    float ss[4] = {0.f, 0.f, 0.f, 0.f};
    #pragma unroll
    for (int c = 0; c < 4; c++)
      #pragma unroll
      for (int j = 0; j < 4; j++) {
        float vv = acc[c][j];
        dst[(bh*1024 + s_base + j) * 64 + c*16 + lr] = bfbits(vv);
        ss[j] += vv * vv;
      }
    #pragma unroll
    for (int j = 0; j < 4; j++) {
      #pragma unroll
      for (int o = 1; o < 16; o <<= 1) ss[j] += __shfl_xor(ss[j], o);
    }
    if (lr == 0) {
      #pragma unroll
      for (int j = 0; j < 4; j++) sq[bh*1024 + s_base + j] = ss[j];
    }
  }
}

// ---------------- fused product-manifold attention ----------------
// 8 waves/WG: waves 0-3 = t in [0,512), waves 4-7 = t in [512,1024).
// Swapped QK^T: mfma(K,Q) -> D[t][q] with q = lane&15 (so q-row quantities are
// per-lane scalars). No online max (sim <= 0 always). PV = mfma(V^T, P^T).
__global__ __launch_bounds__(512) void attn_kernel(
    const u16* __restrict__ q, const u16* __restrict__ k, const u16* __restrict__ vt,
    const float* __restrict__ qsqA, const float* __restrict__ ksqA,
    const float* __restrict__ gw, const float* __restrict__ temp,
    u16* __restrict__ attnb) {
  int bh = blockIdx.y;
  int b = bh >> 3, head = bh & 7;
  int tid = threadIdx.x;
  int wave = tid >> 6;
  int split = wave >> 2;
  int wq = wave & 3;
  int lane = tid & 63;
  int lr = lane & 15, lg = lane >> 4;
  int q0 = blockIdx.x * 64 + wq * 16;

  const u16* qp = q  + bh * 65536;
  const u16* kp = k  + bh * 65536;
  const u16* vp = vt + bh * 65536;

  __shared__ float ks_s[1024], rkn_s[1024];
  __shared__ u16 plds[8][640];        // per-wave P^T staging, 16 q-rows x 40 u16
  __shared__ float combA[4][1024];    // split-1 acc handoff
  __shared__ float combL[4][64];

  for (int i = tid; i < 1024; i += 512) {
    float kv = ksqA[bh * 1024 + i];
    ks_s[i] = kv;
    rkn_s[i] = rcp_r(sqrt_r(kv) + 1e-8f);
  }
  __syncthreads();

  float g0 = gw[head*3], g1 = gw[head*3+1], g2 = gw[head*3+2];
  float gm = fmaxf(g0, fmaxf(g1, g2));
  float e0 = __expf(g0-gm), e1 = __expf(g1-gm), e2 = __expf(g2-gm);
  float gi = rcp_r(e0 + e1 + e2);
  float tp = temp[head];
  const float LOG2E = 1.4426950408889634f;
  float chn = -e0*gi*tp;          // hyp term stays in log2 domain: exact fold
  float cen = -e1*gi*tp*LOG2E;
  float csn = -e2*gi*tp*LOG2E;

  const u16* qr = qp + (q0 + lr) * 64 + lg * 8;
  bf16x8 aq0 = *reinterpret_cast<const bf16x8a*>(qr);
  bf16x8 aq1 = *reinterpret_cast<const bf16x8a*>(qr + 32);
  float qs  = qsqA[bh*1024 + q0 + lr];
  float omq = 1.f - qs;
  float rqn = rcp_r(sqrt_r(qs) + 1e-8f);

  f32x4 acc[4];
  #pragma unroll
  for (int c = 0; c < 4; c++)
    #pragma unroll
    for (int j = 0; j < 4; j++) acc[c][j] = 0.f;
  float psum = 0.f;
  u16* pw = &plds[wave][0];

  for (int it = 0; it < 16; ++it) {
    int t0 = split * 512 + it * 32;
    const u16* kr = kp + (t0 + lr) * 64 + lg * 8;
    bf16x8 k00 = *reinterpret_cast<const bf16x8a*>(kr);
    bf16x8 k01 = *reinterpret_cast<const bf16x8a*>(kr + 32);
    bf16x8 k10 = *reinterpret_cast<const bf16x8a*>(kr + 1024);
    bf16x8 k11 = *reinterpret_cast<const bf16x8a*>(kr + 1024 + 32);
    f32x4 s0, s1;
    #pragma unroll
    for (int j = 0; j < 4; j++) { s0[j] = 0.f; s1[j] = 0.f; }
    s0 = __builtin_amdgcn_mfma_f32_16x16x32_bf16(k00, aq0, s0, 0, 0, 0);
    s0 = __builtin_amdgcn_mfma_f32_16x16x32_bf16(k01, aq1, s0, 0, 0, 0);
    s1 = __builtin_amdgcn_mfma_f32_16x16x32_bf16(k10, aq0, s1, 0, 0, 0);
    s1 = __builtin_amdgcn_mfma_f32_16x16x32_bf16(k11, aq1, s1, 0, 0, 0);

    f32x4 kq0 = *reinterpret_cast<const f32x4a*>(&ks_s[t0 + 4*lg]);
    f32x4 kq1 = *reinterpret_cast<const f32x4a*>(&ks_s[t0 + 16 + 4*lg]);
    f32x4 rk0 = *reinterpret_cast<const f32x4a*>(&rkn_s[t0 + 4*lg]);
    f32x4 rk1 = *reinterpret_cast<const f32x4a*>(&rkn_s[t0 + 16 + 4*lg]);

    float pv0[4], pv1[4];
    #pragma unroll
    for (int tc = 0; tc < 2; tc++) {
      f32x4 sv = tc ? s1 : s0;
      f32x4 kq = tc ? kq1 : kq0;
      f32x4 rk = tc ? rk1 : rk0;
      float* pv = tc ? pv1 : pv0;
      #pragma unroll
      for (int j = 0; j < 4; j++) {
        float qk  = sv[j];
        float ksj = kq[j];
        float dsq = fmaxf(fmaf(qk, -2.f, qs + ksj), 0.f);
        float euc = sqrt_r(dsq + 1e-8f);
        float den = fmaf(omq, 1.f - ksj, 1e-8f);
        float u   = (dsq + dsq) * rcp_r(den);
        u = fminf(fmaxf(u, 0.f), 999999.f);      // == clip(cosh_arg,1,1e6)-1
        float hyp2 = log2_r((u + 1.f) + sqrt_r(u * (u + 2.f)));  // log2(acosh arg)
        float ca = qk * rqn * rk[j];
        ca = fminf(fmaxf(ca, -1.f), 1.f);
        float aa = fabsf(ca);
        float pp = fmaf(aa, -0.0187293f, 0.0742610f);
        pp = fmaf(aa, pp, -0.2121144f);
        pp = fmaf(aa, pp, 1.5707288f);
        float rr = sqrt_r(1.f - aa) * pp;
        float sph = ca < 0.f ? 3.14159265358979f - rr : rr;
        float sim2 = fmaf(chn, hyp2, fmaf(cen, euc, csn * sph));
        float p = exp2_r(sim2);
        psum += p;
        pv[j] = p;
      }
    }
    // pack P^T into wave-private LDS: row = q (lr), byte col = 2*t_local
    u32 w0 = cvt_pk_bf16(pv0[0], pv0[1]);
    u32 w1 = cvt_pk_bf16(pv0[2], pv0[3]);
    u32 w2 = cvt_pk_bf16(pv1[0], pv1[1]);
    u32 w3 = cvt_pk_bf16(pv1[2], pv1[3]);
    *reinterpret_cast<uint2a*>(pw + lr*40 + 4*lg)      = make_uint2(w0, w1);
    *reinterpret_cast<uint2a*>(pw + lr*40 + 16 + 4*lg) = make_uint2(w2, w3);
    bf16x8 pa = *reinterpret_cast<const bf16x8a*>(pw + lr*40 + lg*8);
    #pragma unroll
    for (int c = 0; c < 4; c++) {
      bf16x8 av = *reinterpret_cast<const bf16x8a*>(vp + (c*16 + lr)*1024 + t0 + lg*8);
      acc[c] = __builtin_amdgcn_mfma_f32_16x16x32_bf16(av, pa, acc[c], 0, 0, 0);
    }
  }

  float lt = psum;
  lt += __shfl_xor(lt, 16);
  lt += __shfl_xor(lt, 32);

  if (split == 1) {
    #pragma unroll
    for (int c = 0; c < 4; c++)
      *reinterpret_cast<f32x4a*>(&combA[wq][lane*16 + c*4]) = acc[c];
    combL[wq][lane] = lt;
  }
  __syncthreads();
  if (split == 0) {
    float rl = rcp_r(lt + combL[wq][lane]);
    #pragma unroll
    for (int c = 0; c < 4; c++) {
      f32x4 o = acc[c] + *reinterpret_cast<const f32x4a*>(&combA[wq][lane*16 + c*4]);
      ushort4 st;
      st.x = bfbits(o[0]*rl); st.y = bfbits(o[1]*rl);
      st.z = bfbits(o[2]*rl); st.w = bfbits(o[3]*rl);
      *reinterpret_cast<ushort4*>(
          &attnb[(size_t)((b << 10) + q0 + lr) * 512 + head*64 + c*16 + 4*lg]) = st;
    }
  }
}

// ---------------- generic  Y = epilogue(X @ W^T + bias) ----------------
// MODE 0: outf = acc + bias + res   MODE 1: outb = bf16(gelu)   MODE 2: like 0 + gw softmax
template<int K, int MODE>
__global__ __launch_bounds__(256) void gemm_kernel(
    const u16* __restrict__ X, const u16* __restrict__ W,
    const float* __restrict__ bias, const float* __restrict__ res,
    float* __restrict__ outf, u16* __restrict__ outb,
    const float* __restrict__ gw, float* __restrict__ wout) {
  constexpr int NS = (MODE == 1) ? 2048 : 512;
  int wave = threadIdx.x >> 6, lane = threadIdx.x & 63;
  int lr = lane & 15, lg = lane >> 4;
  int m0 = blockIdx.x * 128 + wave * 32;
  int n0 = blockIdx.y * 64;
  f32x4 acc[2][4];
  #pragma unroll
  for (int r = 0; r < 2; r++)
    #pragma unroll
    for (int c = 0; c < 4; c++)
      #pragma unroll
      for (int j = 0; j < 4; j++) acc[r][c][j] = 0.f;
  const u16* Xr0 = X + (m0 + lr) * K + lg * 8;
  const u16* Xr1 = Xr0 + 16 * K;
  const u16* Wr  = W + (n0 + lr) * K + lg * 8;
  #pragma unroll 4
  for (int kk = 0; kk < K; kk += 32) {
    bf16x8 a0 = *reinterpret_cast<const bf16x8a*>(Xr0 + kk);
    bf16x8 a1 = *reinterpret_cast<const bf16x8a*>(Xr1 + kk);
    #pragma unroll
    for (int c = 0; c < 4; c++) {
      bf16x8 bw = *reinterpret_cast<const bf16x8a*>(Wr + c*16*K + kk);
      acc[0][c] = __builtin_amdgcn_mfma_f32_16x16x32_bf16(a0, bw, acc[0][c], 0, 0, 0);
      acc[1][c] = __builtin_amdgcn_mfma_f32_16x16x32_bf16(a1, bw, acc[1][c], 0, 0, 0);
    }
  }
  #pragma unroll
  for (int r = 0; r < 2; r++)
    #pragma unroll
    for (int c = 0; c < 4; c++) {
      int col = n0 + c*16 + lr;
      float bb = bias[col];
      #pragma unroll
      for (int j = 0; j < 4; j++) {
        int row = m0 + r*16 + 4*lg + j;
        float v = acc[r][c][j] + bb;
        if (MODE == 0 || MODE == 2) {
          outf[row*NS + col] = v + res[row*NS + col];
        } else {
          float g = 0.5f * v * (1.f + erff(v * 0.70710678118f));
          outb[row*NS + col] = bfbits(g);
        }
      }
    }
  if (MODE == 2) {
    if (blockIdx.x == 0 && blockIdx.y == 0 && threadIdx.x < 8) {
      int h = threadIdx.x;
      float a0 = gw[h*3], a1 = gw[h*3+1], a2 = gw[h*3+2];
      float m = fmaxf(a0, fmaxf(a1, a2));
      float x0 = __expf(a0-m), x1 = __expf(a1-m), x2 = __expf(a2-m);
      float inv = rcp_r(x0 + x1 + x2);
      wout[h*3+0] = x0*inv; wout[h*3+1] = x1*inv; wout[h*3+2] = x2*inv;
    }
  }
}

extern "C" void kernel_launch(void* const* d_in, const int* in_sizes, int n_in,
                              void* d_out, int out_size, void* d_ws, size_t ws_size,
                              hipStream_t stream) {
  const float* x    = (const float*)d_in[0];
  const float* Wq   = (const float*)d_in[1];
  const float* Wk   = (const float*)d_in[2];
  const float* Wv   = (const float*)d_in[3];
  const float* gw   = (const float*)d_in[4];
  const float* temp = (const float*)d_in[5];
  const float* Wo   = (const float*)d_in[6];
  const float* bo   = (const float*)d_in[7];
  const float* ln1w = (const float*)d_in[8];
  const float* ln1b = (const float*)d_in[9];
  const float* ln2w = (const float*)d_in[10];
  const float* ln2b = (const float*)d_in[11];
  const float* W1   = (const float*)d_in[12];
  const float* b1   = (const float*)d_in[13];
  const float* W2   = (const float*)d_in[14];
  const float* b2   = (const float*)d_in[15];

  char* ws = (char*)d_ws;
  u16*  wqb  = (u16*)(ws + 0);
  u16*  wkb  = (u16*)(ws + 65536);
  u16*  wvb  = (u16*)(ws + 131072);
  u16*  wob  = (u16*)(ws + 196608);
  u16*  w1b  = (u16*)(ws + 720896);
  u16*  w2b  = (u16*)(ws + 2818048);
  u16*  h1b  = (u16*)(ws + 4915200);
  u16*  qb   = (u16*)(ws + 9109504);
  u16*  kb   = (u16*)(ws + 13303808);
  u16*  vtb  = (u16*)(ws + 17498112);
  float* qsq = (float*)(ws + 21692416);
  float* ksq = (float*)(ws + 21823488);
  u16*  attnb= (u16*)(ws + 21954560);
  float* x1  = (float*)(ws + 26148864);
  u16*  h2b  = (u16*)(ws + 34537472);
  u16*  gb   = (u16*)(ws + 4915200);   // aliases h1b/qb/kb/vtb/qsq/ksq (dead before FF1)

  float* outf = (float*)d_out;
  float* wout = outf + 4096*512;

  convert_weights<<<2400, 256, 0, stream>>>(Wq, Wk, Wv, Wo, W1, W2,
                                            wqb, wkb, wvb, wob, w1b, w2b);
  ln_kernel<<<4096, 128, 0, stream>>>(x, ln1w, ln1b, h1b);
  qkv_kernel<<<dim3(64, 8, 3), 256, 0, stream>>>(h1b, wqb, wkb, wvb, qb, kb, vtb, qsq, ksq);
  attn_kernel<<<dim3(16, 32), 512, 0, stream>>>(qb, kb, vtb, qsq, ksq, gw, temp, attnb);
  gemm_kernel<512, 0><<<dim3(32, 8), 256, 0, stream>>>(attnb, wob, bo, x, x1, nullptr, nullptr, nullptr);
  ln_kernel<<<4096, 128, 0, stream>>>(x1, ln2w, ln2b, h2b);
  gemm_kernel<512, 1><<<dim3(32, 32), 256, 0, stream>>>(h2b, w1b, b1, nullptr, nullptr, gb, nullptr, nullptr);
  gemm_kernel<2048, 2><<<dim3(32, 8), 256, 0, stream>>>(gb, w2b, b2, x1, outf, nullptr, gw, wout);
}

// Round 3
// 232.646 us; speedup vs baseline: 1.8534x; 1.2549x over previous
//
#include <hip/hip_runtime.h>
#include <hip/hip_bf16.h>
#include <math.h>

typedef __attribute__((ext_vector_type(4))) float f32x4;
typedef __attribute__((ext_vector_type(8))) short bf16x8;
typedef unsigned short u16;
typedef unsigned int u32;

typedef f32x4  __attribute__((may_alias)) f32x4a;
typedef bf16x8 __attribute__((may_alias)) bf16x8a;
typedef uint2  __attribute__((may_alias)) uint2a;

__device__ __forceinline__ u16 bfbits(float f) {
  union { __hip_bfloat16 h; u16 u; } cv;
  cv.h = __float2bfloat16(f);
  return cv.u;
}
__device__ __forceinline__ float rcp_r(float x)  { return __builtin_amdgcn_rcpf(x); }
__device__ __forceinline__ float sqrt_r(float x) { return __builtin_amdgcn_sqrtf(x); }
__device__ __forceinline__ float log2_r(float x) { return __builtin_amdgcn_logf(x); }
__device__ __forceinline__ float exp2_r(float x) { return __builtin_amdgcn_exp2f(x); }
__device__ __forceinline__ u32 cvt_pk_bf16(float lo, float hi) {
  u32 r;
  asm("v_cvt_pk_bf16_f32 %0, %1, %2" : "=v"(r) : "v"(lo), "v"(hi));
  return r;
}
typedef const __attribute__((address_space(1))) unsigned int* gas_t;
typedef __attribute__((address_space(3))) unsigned int* las_t;
__device__ __forceinline__ void gload_lds16(const u16* g, u16* l) {
  __builtin_amdgcn_global_load_lds((gas_t)g, (las_t)l, 16, 0, 0);
}

// ---------------- weight fp32 -> bf16 ----------------
__global__ __launch_bounds__(256) void convert_weights(
    const float* __restrict__ wq, const float* __restrict__ wk, const float* __restrict__ wv,
    const float* __restrict__ wo, const float* __restrict__ w1, const float* __restrict__ w2,
    u16* __restrict__ owq, u16* __restrict__ owk, u16* __restrict__ owv,
    u16* __restrict__ owo, u16* __restrict__ ow1, u16* __restrict__ ow2) {
  int i = blockIdx.x * 256 + threadIdx.x;  // float4 index, total 614400
  const float* src; u16* dst; int base;
  if (i < 8192)        { src = wq; dst = owq; base = 0; }
  else if (i < 16384)  { src = wk; dst = owk; base = 8192; }
  else if (i < 24576)  { src = wv; dst = owv; base = 16384; }
  else if (i < 90112)  { src = wo; dst = owo; base = 24576; }
  else if (i < 352256) { src = w1; dst = ow1; base = 90112; }
  else                 { src = w2; dst = ow2; base = 352256; }
  int li = i - base;
  float4 v = reinterpret_cast<const float4*>(src)[li];
  ushort4 o;
  o.x = bfbits(v.x); o.y = bfbits(v.y); o.z = bfbits(v.z); o.w = bfbits(v.w);
  reinterpret_cast<ushort4*>(dst)[li] = o;
}

// ---------------- layernorm ----------------
__global__ __launch_bounds__(128) void ln_kernel(const float* __restrict__ x,
    const float* __restrict__ w, const float* __restrict__ b, u16* __restrict__ out) {
  int row = blockIdx.x, tid = threadIdx.x;
  float4 v = reinterpret_cast<const float4*>(x + row * 512)[tid];
  float s  = v.x + v.y + v.z + v.w;
  float s2 = v.x*v.x + v.y*v.y + v.z*v.z + v.w*v.w;
  #pragma unroll
  for (int o = 32; o > 0; o >>= 1) { s += __shfl_down(s, o); s2 += __shfl_down(s2, o); }
  __shared__ float sm[4];
  if ((tid & 63) == 0) { sm[(tid >> 6)*2] = s; sm[(tid >> 6)*2 + 1] = s2; }
  __syncthreads();
  float ts = sm[0] + sm[2], ts2 = sm[1] + sm[3];
  float mean = ts * (1.f/512.f);
  float var  = ts2 * (1.f/512.f) - mean*mean;
  float rstd = __builtin_amdgcn_rsqf(var + 1e-5f);
  float4 wv = reinterpret_cast<const float4*>(w)[tid];
  float4 bv = reinterpret_cast<const float4*>(b)[tid];
  ushort4 o;
  o.x = bfbits((v.x-mean)*rstd*wv.x + bv.x);
  o.y = bfbits((v.y-mean)*rstd*wv.y + bv.y);
  o.z = bfbits((v.z-mean)*rstd*wv.z + bv.z);
  o.w = bfbits((v.w-mean)*rstd*wv.w + bv.w);
  reinterpret_cast<ushort4*>(out + row * 512)[tid] = o;
}

// ---------------- QKV projection (q,k,v in one pass; A-frags loaded once) ----------------
__global__ __launch_bounds__(256) void qkv_kernel(const u16* __restrict__ h1,
    const u16* __restrict__ wqb, const u16* __restrict__ wkb, const u16* __restrict__ wvb,
    u16* __restrict__ q, u16* __restrict__ k, u16* __restrict__ vt,
    float* __restrict__ qsq, float* __restrict__ ksq) {
  int mt = blockIdx.x, head = blockIdx.y;
  int wave = threadIdx.x >> 6, lane = threadIdx.x & 63;
  int lr = lane & 15, lg = lane >> 4;
  int m0 = mt * 64 + wave * 16;
  const u16* xr = h1 + (m0 + lr) * 512 + head * 64 + lg * 8;
  bf16x8 a0 = *reinterpret_cast<const bf16x8a*>(xr);
  bf16x8 a1 = *reinterpret_cast<const bf16x8a*>(xr + 32);
  int m_base = m0 + 4*lg;
  int bq = m_base >> 10;
  int s_base = m_base & 1023;
  int bh = (bq << 3) + head;
  #pragma unroll 1
  for (int mat = 0; mat < 3; ++mat) {
    const u16* W = (mat == 0 ? wqb : mat == 1 ? wkb : wvb) + head * 4096;
    f32x4 acc[4];
    #pragma unroll
    for (int c = 0; c < 4; c++)
      #pragma unroll
      for (int j = 0; j < 4; j++) acc[c][j] = 0.f;
    #pragma unroll
    for (int c = 0; c < 4; c++) {
      const u16* wr = W + (c*16 + lr) * 64 + lg * 8;
      bf16x8 b0 = *reinterpret_cast<const bf16x8a*>(wr);
      bf16x8 b1 = *reinterpret_cast<const bf16x8a*>(wr + 32);
      acc[c] = __builtin_amdgcn_mfma_f32_16x16x32_bf16(a0, b0, acc[c], 0, 0, 0);
      acc[c] = __builtin_amdgcn_mfma_f32_16x16x32_bf16(a1, b1, acc[c], 0, 0, 0);
    }
    if (mat == 2) {
      #pragma unroll
      for (int c = 0; c < 4; c++)
        #pragma unroll
        for (int j = 0; j < 4; j++)
          vt[(bh*64 + c*16 + lr) * 1024 + s_base + j] = bfbits(acc[c][j]);
    } else {
      u16* dst = (mat == 0 ? q : k);
      float* sq = (mat == 0 ? qsq : ksq);
      float ss[4] = {0.f, 0.f, 0.f, 0.f};
      #pragma unroll
      for (int c = 0; c < 4; c++)
        #pragma unroll
        for (int j = 0; j < 4; j++) {
          float vv = acc[c][j];
          dst[(bh*1024 + s_base + j) * 64 + c*16 + lr] = bfbits(vv);
          ss[j] += vv * vv;
        }
      #pragma unroll
      for (int j = 0; j < 4; j++) {
        #pragma unroll
        for (int o = 1; o < 16; o <<= 1) ss[j] += __shfl_xor(ss[j], o);
      }
      if (lr == 0) {
        #pragma unroll
        for (int j = 0; j < 4; j++) sq[bh*1024 + s_base + j] = ss[j];
      }
    }
  }
}

// ---------------- fused product-manifold attention ----------------
// q-tile 32 (2 q-waves) x 4 t-splits = 8 waves; grid (32,32)=1024 WGs -> 4 WG/CU.
// Swapped QK^T (q = lane&15), no online max (sim <= 0). PV = mfma(V^T, P^T).
// P-staging LDS unioned with the split-reduction buffer (40.4 KB total/WG).
__global__ __launch_bounds__(512) void attn_kernel(
    const u16* __restrict__ q, const u16* __restrict__ k, const u16* __restrict__ vt,
    const float* __restrict__ qsqA, const float* __restrict__ ksqA,
    const float* __restrict__ gw, const float* __restrict__ temp,
    u16* __restrict__ attnb) {
  int bh = blockIdx.y;
  int b = bh >> 3, head = bh & 7;
  int tid = threadIdx.x;
  int wave = tid >> 6;
  int wq = wave & 1;       // q sub-tile
  int split = wave >> 1;   // t-split 0..3
  int lane = tid & 63;
  int lr = lane & 15, lg = lane >> 4;
  int q0 = blockIdx.x * 32 + wq * 16;

  const u16* qp = q  + bh * 65536;
  const u16* kp = k  + bh * 65536;
  const u16* vp = vt + bh * 65536;

  __shared__ float ks_s[1024], rkn_s[1024];
  __shared__ __align__(16) char umem[32256];   // union: plds[8][640]u16 | accR+lR
  u16* pw = (u16*)umem + wave * 640;           // wave-private P^T staging
  float* accR = (float*)umem;                  // [(wq*3+s)*64+lane]*20 + c*4  (80B stride)
  float* lR   = (float*)(umem + 30720);        // [(wq*3+s)*64+lane]

  for (int i = tid; i < 1024; i += 512) {
    float kv = ksqA[bh * 1024 + i];
    ks_s[i] = kv;
    rkn_s[i] = rcp_r(sqrt_r(kv) + 1e-8f);
  }
  __syncthreads();

  float g0 = gw[head*3], g1 = gw[head*3+1], g2 = gw[head*3+2];
  float gm = fmaxf(g0, fmaxf(g1, g2));
  float e0 = __expf(g0-gm), e1 = __expf(g1-gm), e2 = __expf(g2-gm);
  float gi = rcp_r(e0 + e1 + e2);
  float tp = temp[head];
  const float LOG2E = 1.4426950408889634f;
  float chn = -e0*gi*tp;          // hyp term stays in log2 domain: exact fold
  float cen = -e1*gi*tp*LOG2E;
  float csn = -e2*gi*tp*LOG2E;

  const u16* qr = qp + (q0 + lr) * 64 + lg * 8;
  bf16x8 aq0 = *reinterpret_cast<const bf16x8a*>(qr);
  bf16x8 aq1 = *reinterpret_cast<const bf16x8a*>(qr + 32);
  float qs  = qsqA[bh*1024 + q0 + lr];
  float omq = 1.f - qs;
  float rqn = rcp_r(sqrt_r(qs) + 1e-8f);

  f32x4 acc[4];
  #pragma unroll
  for (int c = 0; c < 4; c++)
    #pragma unroll
    for (int j = 0; j < 4; j++) acc[c][j] = 0.f;
  float psum0 = 0.f, psum1 = 0.f;

  for (int it = 0; it < 8; ++it) {
    int t0 = split * 256 + it * 32;
    const u16* kr = kp + (t0 + lr) * 64 + lg * 8;
    bf16x8 k00 = *reinterpret_cast<const bf16x8a*>(kr);
    bf16x8 k01 = *reinterpret_cast<const bf16x8a*>(kr + 32);
    bf16x8 k10 = *reinterpret_cast<const bf16x8a*>(kr + 1024);
    bf16x8 k11 = *reinterpret_cast<const bf16x8a*>(kr + 1024 + 32);
    f32x4 s0, s1;
    #pragma unroll
    for (int j = 0; j < 4; j++) { s0[j] = 0.f; s1[j] = 0.f; }
    s0 = __builtin_amdgcn_mfma_f32_16x16x32_bf16(k00, aq0, s0, 0, 0, 0);
    s0 = __builtin_amdgcn_mfma_f32_16x16x32_bf16(k01, aq1, s0, 0, 0, 0);
    s1 = __builtin_amdgcn_mfma_f32_16x16x32_bf16(k10, aq0, s1, 0, 0, 0);
    s1 = __builtin_amdgcn_mfma_f32_16x16x32_bf16(k11, aq1, s1, 0, 0, 0);

    f32x4 kq0 = *reinterpret_cast<const f32x4a*>(&ks_s[t0 + 4*lg]);
    f32x4 kq1 = *reinterpret_cast<const f32x4a*>(&ks_s[t0 + 16 + 4*lg]);
    f32x4 rk0 = *reinterpret_cast<const f32x4a*>(&rkn_s[t0 + 4*lg]);
    f32x4 rk1 = *reinterpret_cast<const f32x4a*>(&rkn_s[t0 + 16 + 4*lg]);

    float pv0[4], pv1[4];
    #pragma unroll
    for (int tc = 0; tc < 2; tc++) {
      f32x4 sv = tc ? s1 : s0;
      f32x4 kq = tc ? kq1 : kq0;
      f32x4 rk = tc ? rk1 : rk0;
      float* pv = tc ? pv1 : pv0;
      #pragma unroll
      for (int j = 0; j < 4; j++) {
        float qk  = sv[j];
        float ksj = kq[j];
        float dsq = fmaxf(fmaf(qk, -2.f, qs + ksj), 0.f);
        float euc = sqrt_r(dsq + 1e-8f);
        float den = fmaf(omq, 1.f - ksj, 1e-8f);
        float u   = (dsq + dsq) * rcp_r(den);
        u = fminf(fmaxf(u, 0.f), 999999.f);      // == clip(cosh_arg,1,1e6)-1
        float hyp2 = log2_r((u + 1.f) + sqrt_r(u * (u + 2.f)));  // acosh * log2e
        float ca = qk * rqn * rk[j];
        ca = fminf(fmaxf(ca, -1.f), 1.f);
        float aa = fabsf(ca);
        float pp = fmaf(aa, -0.0187293f, 0.0742610f);
        pp = fmaf(aa, pp, -0.2121144f);
        pp = fmaf(aa, pp, 1.5707288f);
        float rr = sqrt_r(1.f - aa) * pp;
        float sph = ca < 0.f ? 3.14159265358979f - rr : rr;
        float sim2 = fmaf(chn, hyp2, fmaf(cen, euc, csn * sph));
        float p = exp2_r(sim2);
        if (tc) psum1 += p; else psum0 += p;
        pv[j] = p;
      }
    }
    u32 w0 = cvt_pk_bf16(pv0[0], pv0[1]);
    u32 w1 = cvt_pk_bf16(pv0[2], pv0[3]);
    u32 w2 = cvt_pk_bf16(pv1[0], pv1[1]);
    u32 w3 = cvt_pk_bf16(pv1[2], pv1[3]);
    *reinterpret_cast<uint2a*>(pw + lr*40 + 4*lg)      = make_uint2(w0, w1);
    *reinterpret_cast<uint2a*>(pw + lr*40 + 16 + 4*lg) = make_uint2(w2, w3);
    bf16x8 pa = *reinterpret_cast<const bf16x8a*>(pw + lr*40 + lg*8);
    #pragma unroll
    for (int c = 0; c < 4; c++) {
      bf16x8 av = *reinterpret_cast<const bf16x8a*>(vp + (c*16 + lr)*1024 + t0 + lg*8);
      acc[c] = __builtin_amdgcn_mfma_f32_16x16x32_bf16(av, pa, acc[c], 0, 0, 0);
    }
  }

  float lt = psum0 + psum1;
  lt += __shfl_xor(lt, 16);
  lt += __shfl_xor(lt, 32);

  __syncthreads();   // all waves done with plds before accR overwrites it
  if (split > 0) {
    int base = (wq*3 + split-1)*64 + lane;
    #pragma unroll
    for (int c = 0; c < 4; c++)
      *reinterpret_cast<f32x4a*>(accR + base*20 + c*4) = acc[c];
    lR[base] = lt;
  }
  __syncthreads();
  if (split == 0) {
    float ltot = lt;
    #pragma unroll
    for (int s = 0; s < 3; s++) ltot += lR[(wq*3+s)*64 + lane];
    float rl = rcp_r(ltot);
    #pragma unroll
    for (int c = 0; c < 4; c++) {
      f32x4 o = acc[c];
      #pragma unroll
      for (int s = 0; s < 3; s++)
        o += *reinterpret_cast<const f32x4a*>(accR + ((wq*3+s)*64+lane)*20 + c*4);
      ushort4 st;
      st.x = bfbits(o[0]*rl); st.y = bfbits(o[1]*rl);
      st.z = bfbits(o[2]*rl); st.w = bfbits(o[3]*rl);
      *reinterpret_cast<ushort4*>(
          &attnb[(size_t)((b << 10) + q0 + lr) * 512 + head*64 + c*16 + 4*lg]) = st;
    }
  }
}

// ---------------- tiled GEMM  Y = epilogue(X @ W^T + bias)  (m97 structure) ----------------
// BM=128, BK=32, global_load_lds(16B), XOR slot-swizzle (slot ^= row&3) on both sides.
// BN=128: 4 waves 2x2, wave=64x64.  BN=64: 4 waves 4x1, wave=32x64.
// MODE 0: outf = acc+bias+res   MODE 1: outb = bf16(gelu_tanh)   MODE 2: like 0 + gw softmax
template<int K, int BN, int MODE>
__global__ __launch_bounds__(256) void gemm_kernel(
    const u16* __restrict__ X, const u16* __restrict__ W,
    const float* __restrict__ bias, const float* __restrict__ res,
    float* __restrict__ outf, u16* __restrict__ outb,
    const float* __restrict__ gw, float* __restrict__ wout) {
  constexpr int NS = (MODE == 1) ? 2048 : 512;
  constexpr int BM = 128;
  constexpr int WM = (BN == 128) ? 64 : 32;
  constexpr int NFR = WM / 16;
  __shared__ u16 As[BM * 32];
  __shared__ u16 Bs[BN * 32];
  int tid = threadIdx.x;
  int wave = tid >> 6, lane = tid & 63;
  int lr = lane & 15, lg = lane >> 4;
  int wr = (BN == 128) ? (wave >> 1) : wave;
  int wc = (BN == 128) ? (wave & 1) : 0;
  int m0 = blockIdx.x * BM;
  int n0 = blockIdx.y * BN;
  f32x4 acc[NFR][4];
  #pragma unroll
  for (int fr = 0; fr < NFR; fr++)
    #pragma unroll
    for (int fc = 0; fc < 4; fc++)
      #pragma unroll
      for (int j = 0; j < 4; j++) acc[fr][fc][j] = 0.f;
  // staging: chunk c -> LDS 16B slot c; row=c>>2, slot=c&3; global col pre-swizzled
  int chunk = wave * 64 + lane;
  int arow = chunk >> 2;
  int acol = ((chunk & 3) ^ (arow & 3)) << 3;      // inverse-swizzled source
  const u16* Ag0 = X + (size_t)(m0 + arow) * K + acol;
  const u16* Ag1 = X + (size_t)(m0 + 64 + arow) * K + acol;
  const u16* Bg0 = W + (size_t)(n0 + arow) * K + acol;
  const u16* Bg1 = W + (size_t)(n0 + 64 + arow) * K + acol;
  u16* Al0 = As + wave * 512;
  u16* Al1 = As + 2048 + wave * 512;
  u16* Bl0 = Bs + wave * 512;
  u16* Bl1 = Bs + 2048 + wave * 512;
  // swizzled read cols (u16 units): slot = lg ^ (row&3), row&3 == lr&3
  int rdcol = ((lg ^ (lr & 3)) << 3);
  for (int k0 = 0; k0 < K; k0 += 32) {
    __syncthreads();                 // prev-iter LDS reads complete
    gload_lds16(Ag0 + k0, Al0);
    gload_lds16(Ag1 + k0, Al1);
    gload_lds16(Bg0 + k0, Bl0);
    if constexpr (BN == 128) gload_lds16(Bg1 + k0, Bl1);
    __syncthreads();                 // drains vmcnt -> tile visible
    bf16x8 af[NFR], bfr[4];
    #pragma unroll
    for (int fr = 0; fr < NFR; fr++)
      af[fr] = *reinterpret_cast<const bf16x8a*>(As + (wr*WM + fr*16 + lr)*32 + rdcol);
    #pragma unroll
    for (int fc = 0; fc < 4; fc++)
      bfr[fc] = *reinterpret_cast<const bf16x8a*>(Bs + (wc*64 + fc*16 + lr)*32 + rdcol);
    #pragma unroll
    for (int fr = 0; fr < NFR; fr++)
      #pragma unroll
      for (int fc = 0; fc < 4; fc++)
        acc[fr][fc] = __builtin_amdgcn_mfma_f32_16x16x32_bf16(af[fr], bfr[fc], acc[fr][fc], 0, 0, 0);
  }
  #pragma unroll
  for (int fr = 0; fr < NFR; fr++)
    #pragma unroll
    for (int fc = 0; fc < 4; fc++) {
      int col = n0 + wc*64 + fc*16 + lr;
      float bb = bias[col];
      #pragma unroll
      for (int j = 0; j < 4; j++) {
        int row = m0 + wr*WM + fr*16 + 4*lg + j;
        float v = acc[fr][fc][j] + bb;
        if (MODE == 0 || MODE == 2) {
          outf[(size_t)row*NS + col] = v + res[(size_t)row*NS + col];
        } else {
          // tanh-form gelu via exp2/rcp: gelu(v) ~= v * sigmoid(2*0.79788(v+0.044715 v^3))
          float t = v * fmaf(v*v, 0.035677408137f, 0.7978845608f);
          float g = v * rcp_r(1.f + exp2_r(-2.8853900817779268f * t));
          outb[(size_t)row*NS + col] = bfbits(g);
        }
      }
    }
  if (MODE == 2) {
    if (blockIdx.x == 0 && blockIdx.y == 0 && threadIdx.x < 8) {
      int h = threadIdx.x;
      float a0 = gw[h*3], a1 = gw[h*3+1], a2 = gw[h*3+2];
      float m = fmaxf(a0, fmaxf(a1, a2));
      float x0 = __expf(a0-m), x1 = __expf(a1-m), x2 = __expf(a2-m);
      float inv = rcp_r(x0 + x1 + x2);
      wout[h*3+0] = x0*inv; wout[h*3+1] = x1*inv; wout[h*3+2] = x2*inv;
    }
  }
}

extern "C" void kernel_launch(void* const* d_in, const int* in_sizes, int n_in,
                              void* d_out, int out_size, void* d_ws, size_t ws_size,
                              hipStream_t stream) {
  const float* x    = (const float*)d_in[0];
  const float* Wq   = (const float*)d_in[1];
  const float* Wk   = (const float*)d_in[2];
  const float* Wv   = (const float*)d_in[3];
  const float* gw   = (const float*)d_in[4];
  const float* temp = (const float*)d_in[5];
  const float* Wo   = (const float*)d_in[6];
  const float* bo   = (const float*)d_in[7];
  const float* ln1w = (const float*)d_in[8];
  const float* ln1b = (const float*)d_in[9];
  const float* ln2w = (const float*)d_in[10];
  const float* ln2b = (const float*)d_in[11];
  const float* W1   = (const float*)d_in[12];
  const float* b1   = (const float*)d_in[13];
  const float* W2   = (const float*)d_in[14];
  const float* b2   = (const float*)d_in[15];

  char* ws = (char*)d_ws;
  u16*  wqb  = (u16*)(ws + 0);
  u16*  wkb  = (u16*)(ws + 65536);
  u16*  wvb  = (u16*)(ws + 131072);
  u16*  wob  = (u16*)(ws + 196608);
  u16*  w1b  = (u16*)(ws + 720896);
  u16*  w2b  = (u16*)(ws + 2818048);
  u16*  h1b  = (u16*)(ws + 4915200);
  u16*  qb   = (u16*)(ws + 9109504);
  u16*  kb   = (u16*)(ws + 13303808);
  u16*  vtb  = (u16*)(ws + 17498112);
  float* qsq = (float*)(ws + 21692416);
  float* ksq = (float*)(ws + 21823488);
  u16*  attnb= (u16*)(ws + 21954560);
  float* x1  = (float*)(ws + 26148864);
  u16*  h2b  = (u16*)(ws + 34537472);
  u16*  gb   = (u16*)(ws + 4915200);   // aliases h1b/qb/kb/vtb/qsq/ksq (dead before FF1)

  float* outf = (float*)d_out;
  float* wout = outf + 4096*512;

  convert_weights<<<2400, 256, 0, stream>>>(Wq, Wk, Wv, Wo, W1, W2,
                                            wqb, wkb, wvb, wob, w1b, w2b);
  ln_kernel<<<4096, 128, 0, stream>>>(x, ln1w, ln1b, h1b);
  qkv_kernel<<<dim3(64, 8), 256, 0, stream>>>(h1b, wqb, wkb, wvb, qb, kb, vtb, qsq, ksq);
  attn_kernel<<<dim3(32, 32), 512, 0, stream>>>(qb, kb, vtb, qsq, ksq, gw, temp, attnb);
  gemm_kernel<512, 64, 0><<<dim3(32, 8), 256, 0, stream>>>(
      attnb, wob, bo, x, x1, nullptr, nullptr, nullptr);
  ln_kernel<<<4096, 128, 0, stream>>>(x1, ln2w, ln2b, h2b);
  gemm_kernel<512, 128, 1><<<dim3(32, 16), 256, 0, stream>>>(
      h2b, w1b, b1, nullptr, nullptr, gb, nullptr, nullptr);
  gemm_kernel<2048, 64, 2><<<dim3(32, 8), 256, 0, stream>>>(
      gb, w2b, b2, x1, outf, nullptr, gw, wout);
}